// Round 1
// 185.452 us; speedup vs baseline: 1.0214x; 1.0214x over previous
//
#include <hip/hip_runtime.h>

// ---------- types / helpers ----------
typedef __bf16 bf16x8 __attribute__((ext_vector_type(8)));
typedef float f32x4 __attribute__((ext_vector_type(4)));
typedef float f32x16 __attribute__((ext_vector_type(16)));

struct alignas(16) US8 { unsigned short us[8]; };

static __device__ inline unsigned short f2bf(float f) {
  union { float f; unsigned u; } v; v.f = f;
  unsigned r = v.u + 0x7fffu + ((v.u >> 16) & 1u);   // RNE
  return (unsigned short)(r >> 16);
}

static __device__ inline void gload16(const unsigned short* g, unsigned short* l) {
  // direct-to-LDS DMA, 16B/lane; LDS dest = wave-uniform base + lane*16
  __builtin_amdgcn_global_load_lds(
      (const __attribute__((address_space(1))) void*)g,
      (__attribute__((address_space(3))) void*)l, 16, 0, 0);
}

// B=8, N=4096, D=128.  32768 total rows.
#define NSEQ 4096
#define DIM 128
#define ROWS 32768
#define KH 2                      // cross-block key splits in attn

// log2(e)/sqrt(128): folded into q so S exits QK^T already in log2 domain
#define EXPC (1.4426950408889634f * 0.08838834764831845f)

// ---------- prep: weight transposes to bf16, wide (96 blocks) ----------
__global__ void prep_kernel(const float* __restrict__ Wkv, const float* __restrict__ Wp,
                            unsigned short* __restrict__ wkvT, unsigned short* __restrict__ wpT) {
  const int t = threadIdx.x;
  const int d = (t & 63) * 2;
  if (blockIdx.x < 64) {
    const int col = blockIdx.x * 4 + (t >> 6);
    unsigned short lo = f2bf(Wkv[d * 256 + col]);
    unsigned short hi = f2bf(Wkv[(d + 1) * 256 + col]);
    *reinterpret_cast<unsigned*>(&wkvT[col * 128 + d]) = (unsigned)lo | ((unsigned)hi << 16);
  } else {
    const int col = (blockIdx.x - 64) * 4 + (t >> 6);
    unsigned short lo = f2bf(Wp[d * 128 + col]);
    unsigned short hi = f2bf(Wp[(d + 1) * 128 + col]);
    *reinterpret_cast<unsigned*>(&wpT[col * 128 + d]) = (unsigned)lo | ((unsigned)hi << 16);
  }
}

// ---------- kv = x @ Wkv + bkv -> k_bf (row-major), v BLOCKED+PERMUTED; q blocked cast ----------
// 64 rows per block (512 GEMM blocks -> 2 blocks/CU; was 128 rows @ 1 block/CU, latency-bound).
// Blocked V layout per batch: [tile(64 keys)][chunk 16][lane 64][8] where chunk=(mg,dh):
//   element (chunk, l, j) = V[m' = mg*8+j][d = dh*64+l], m' = key order with bit2<->bit3
//   swapped per 16-block (matches 32x32 MFMA C/D->A reg order in attn's PV).
// Blocked q_hat layout per batch: [tile(64 rows)][kc 16][lane 64][8]:
//   element = q_hat[row = tile*64+l][d = kc*8+j].
__global__ __launch_bounds__(256, 2) void kv_kernel(
    const float* __restrict__ x, const unsigned short* __restrict__ wkvT,
    const float* __restrict__ bkv, const float* __restrict__ q,
    unsigned short* __restrict__ kout, unsigned short* __restrict__ vtout,
    unsigned short* __restrict__ qo) {
  const int tid = threadIdx.x;
  if (blockIdx.x >= 512) {                  // q scale+cast tail blocks -> blocked layout
    int i = ((blockIdx.x - 512) * 256 + tid) * 8;
    const float4* p = reinterpret_cast<const float4*>(q + i);
    float4 a = p[0], b = p[1];
    US8 o;
    o.us[0]=f2bf(a.x*EXPC); o.us[1]=f2bf(a.y*EXPC); o.us[2]=f2bf(a.z*EXPC); o.us[3]=f2bf(a.w*EXPC);
    o.us[4]=f2bf(b.x*EXPC); o.us[5]=f2bf(b.y*EXPC); o.us[6]=f2bf(b.z*EXPC); o.us[7]=f2bf(b.w*EXPC);
    int row = i >> 7, d0 = i & 127;
    int bb = row >> 12, n = row & (NSEQ - 1), tile = n >> 6, l = n & 63, kc = d0 >> 3;
    *reinterpret_cast<US8*>(qo + (size_t)bb * NSEQ * DIM + tile * 8192 + kc * 512 + l * 8) = o;
    return;
  }
  __shared__ __align__(16) unsigned short WT[256 * 136];   // [col][d] stride 136 (69.6 KB)
  const int wv = tid >> 6, lane = tid & 63, l16 = lane & 15, quad = lane >> 4;
  const int row0 = blockIdx.x * 64;

  for (int p = 0; p < 16; ++p) {            // 4096 US8 chunks, b128 both sides
    int c = p * 256 + tid;
    int col = c >> 4, c16 = c & 15;
    *reinterpret_cast<US8*>(&WT[col * 136 + c16 * 8]) =
        *reinterpret_cast<const US8*>(wkvT + col * 128 + c16 * 8);
  }
  __syncthreads();

  bf16x8 afrag[4];
  const int arow = row0 + wv * 16 + l16;
  for (int s = 0; s < 4; ++s) {
    const float4* xp = reinterpret_cast<const float4*>(x + (size_t)arow * DIM + s * 32 + quad * 8);
    float4 u0 = xp[0], u1 = xp[1];
    US8 af;
    af.us[0]=f2bf(u0.x); af.us[1]=f2bf(u0.y); af.us[2]=f2bf(u0.z); af.us[3]=f2bf(u0.w);
    af.us[4]=f2bf(u1.x); af.us[5]=f2bf(u1.y); af.us[6]=f2bf(u1.z); af.us[7]=f2bf(u1.w);
    afrag[s] = __builtin_bit_cast(bf16x8, af);
  }
  f32x4 acc[16];
  for (int g = 0; g < 16; ++g) acc[g] = f32x4{0.f, 0.f, 0.f, 0.f};
  for (int s = 0; s < 4; ++s)
    for (int g = 0; g < 16; ++g) {
      bf16x8 bfr = *reinterpret_cast<const bf16x8*>(&WT[(g * 16 + l16) * 136 + s * 32 + quad * 8]);
      acc[g] = __builtin_amdgcn_mfma_f32_16x16x32_bf16(afrag[s], bfr, acc[g], 0, 0, 0);
    }

  // k half: direct stores (row-major)
  for (int g = 0; g < 8; ++g) {
    float bias = bkv[g * 16 + l16];
    for (int r = 0; r < 4; ++r) {
      int orow = row0 + wv * 16 + quad * 4 + r;   // C/D: row=quad*4+r, col=l16
      kout[(size_t)orow * DIM + g * 16 + l16] = f2bf(acc[g][r] + bias);
    }
  }
  // v half: transpose through LDS (stride 72), then blocked+permuted b128 global stores
  __syncthreads();
  unsigned short* LDSt = WT;                // [d][n_local 64] stride 72
  for (int g = 0; g < 8; ++g) {
    float bias = bkv[128 + g * 16 + l16];
    for (int r = 0; r < 4; ++r)
      LDSt[(g * 16 + l16) * 72 + wv * 16 + quad * 4 + r] = f2bf(acc[g + 8][r] + bias);
  }
  __syncthreads();
  const int bb = row0 >> 12;
  const int tile = (row0 & (NSEQ - 1)) >> 6;
  unsigned short* vbo = vtout + (size_t)bb * NSEQ * DIM + (size_t)tile * 8192;
  for (int p = 0; p < 4; ++p) {             // 1024 16B units: 16 chunks x 64 lanes
    int c = p * 256 + tid;
    int idx = c >> 6, l = c & 63;
    int mg = idx >> 1, dh = idx & 1, d = dh * 64 + l;
    int nb = (mg >> 1) * 16 + (mg & 1) * 4;   // first 4-run (bit2<->3 swap)
    uint2 lo = *reinterpret_cast<const uint2*>(&LDSt[d * 72 + nb]);
    uint2 hi = *reinterpret_cast<const uint2*>(&LDSt[d * 72 + nb + 8]);
    uint4 o{lo.x, lo.y, hi.x, hi.y};
    *reinterpret_cast<uint4*>(vbo + (size_t)idx * 512 + l * 8) = o;
  }
}

// ---------- flash attention partials (32x32x16 MFMA, register-P, double-buffered DMA) ----------
// grid 512 = 8 batches (blockIdx&7) x 32 q-tiles (128 rows) x 2 key-splits.
// Block 256 thr = 4 q-waves x 32 rows; TWO 64-key K-hat/V tiles in LDS (64 KB -> 2 blocks/CU).
// Loop = { issue DMA for tile t+1 into other buffer; compute tile t; one __syncthreads }:
// the barrier's implicit vmcnt(0) lands AFTER ~2000 cycles of compute, so the DMA latency
// that was previously exposed between two barriers per iteration is hidden.
__global__ __launch_bounds__(256, 2) void attn_kernel(
    const unsigned short* __restrict__ kbuf, const unsigned short* __restrict__ qblk,
    const unsigned short* __restrict__ vblk,
    float* __restrict__ opart, float* __restrict__ lpart) {
  __shared__ __align__(16) unsigned short SH[32768];   // 2 x (Ksh 8192 | Vsh 8192) = 64 KB
  const int tid = threadIdx.x;
  const int wv = tid >> 6, lane = tid & 63, l32 = lane & 31, h = lane >> 5;
  const int b = blockIdx.x & 7;
  const int t = blockIdx.x >> 3;
  const int q0 = (t & 31) * 128;
  const int kh = t >> 5;
  const int key0 = kh * (NSEQ / KH);
  const unsigned short* kb = kbuf + (size_t)b * NSEQ * DIM;
  const unsigned short* qb = qblk + (size_t)b * NSEQ * DIM;
  const unsigned short* vb = vblk + (size_t)b * NSEQ * DIM;

  // per-lane staging sources: 8 chunks/wave/tile, advance 8192 us per tile.
  // lofs = idx*512 covers K at [0,8192) and V at [8192,16384) within a buffer.
  const unsigned short* gsrc[8];
  int lofs[8];
#pragma unroll
  for (int c = 0; c < 8; ++c) {
    const int idx = wv * 8 + c;
    const unsigned short* p = (idx < 16) ? (qb + idx * 512) : (vb + (size_t)(idx - 16) * 512);
    gsrc[c] = p + (size_t)(key0 >> 6) * 8192 + lane * 8;
    lofs[c] = idx * 512;
  }

  constexpr int NT = NSEQ / KH / 64;
  // prologue: stage tile 0 into buffer 0 (overlaps with kfrag loads below)
#pragma unroll
  for (int c = 0; c < 8; ++c) gload16(gsrc[c], &SH[lofs[c]]);

  // B-operand frags: this wave's 32 q-rows of k. B[k=h*8+j][n=l32]
  bf16x8 kfrag[8];
  for (int ks = 0; ks < 8; ++ks)
    kfrag[ks] = __builtin_bit_cast(bf16x8, *reinterpret_cast<const US8*>(
        kb + (size_t)(q0 + wv * 32 + l32) * DIM + ks * 16 + h * 8));

  f32x16 Oacc[4];
  for (int dt = 0; dt < 4; ++dt)
    for (int i = 0; i < 16; ++i) Oacc[dt][i] = 0.f;
  float lsum = 0.f;

  __syncthreads();                          // tile 0 staged (vmcnt(0) + barrier)

  for (int it = 0; it < NT; ++it) {
    const int cur = (it & 1) << 14;         // 0 / 16384
    if (it + 1 < NT) {                      // issue next tile's DMA into other buffer
      const int nxt = cur ^ 16384;
#pragma unroll
      for (int c = 0; c < 8; ++c)
        gload16(gsrc[c] + (size_t)(it + 1) * 8192, &SH[nxt + lofs[c]]);
    }
    const unsigned short* Ksh = SH + cur;
    const unsigned short* Vsh = Ksh + 8192;

    // S^T tiles: D[m 32][n 32] = sum_ks A(K-hat)[m][k] * B(k-rows)[k][n]
    f32x16 S0, S1;
    for (int i = 0; i < 16; ++i) { S0[i] = 0.f; S1[i] = 0.f; }
    for (int ks = 0; ks < 8; ++ks) {
      const unsigned short* kc = &Ksh[(ks * 2 + h) * 512];
      bf16x8 a0 = *reinterpret_cast<const bf16x8*>(&kc[l32 * 8]);
      bf16x8 a1 = *reinterpret_cast<const bf16x8*>(&kc[(32 + l32) * 8]);
      S0 = __builtin_amdgcn_mfma_f32_32x32x16_bf16(a0, kfrag[ks], S0, 0, 0, 0);
      S1 = __builtin_amdgcn_mfma_f32_32x32x16_bf16(a1, kfrag[ks], S1, 0, 0, 0);
    }

    // P = exp2(S^T) truncated to bf16, packed in-lane: frag (T,s) = regs s*8..s*8+7
    bf16x8 pf[2][2];
    for (int T = 0; T < 2; ++T) {
      unsigned pk[8];
      for (int i2 = 0; i2 < 8; ++i2) {
        float e0 = exp2f(T ? S1[i2 * 2] : S0[i2 * 2]);
        float e1 = exp2f(T ? S1[i2 * 2 + 1] : S0[i2 * 2 + 1]);
        unsigned u0 = __builtin_bit_cast(unsigned, e0) & 0xffff0000u;
        unsigned u1 = __builtin_bit_cast(unsigned, e1) & 0xffff0000u;
        lsum += __builtin_bit_cast(float, u0) + __builtin_bit_cast(float, u1);
        pk[i2] = (u0 >> 16) | u1;
      }
      pf[T][0] = __builtin_bit_cast(bf16x8, uint4{pk[0], pk[1], pk[2], pk[3]});
      pf[T][1] = __builtin_bit_cast(bf16x8, uint4{pk[4], pk[5], pk[6], pk[7]});
    }

    // O[n][d] += P[n][m] * V[m][d]: A = pf (regs), B = Vsh chunks (mg = 4T+2s+h)
    for (int T = 0; T < 2; ++T)
      for (int s = 0; s < 2; ++s) {
        const int mg = 4 * T + 2 * s + h;
        for (int dt = 0; dt < 4; ++dt) {
          bf16x8 bv = *reinterpret_cast<const bf16x8*>(
              &Vsh[(mg * 2 + (dt >> 1)) * 512 + ((dt & 1) * 32 + l32) * 8]);
          Oacc[dt] = __builtin_amdgcn_mfma_f32_32x32x16_bf16(pf[T][s], bv, Oacc[dt], 0, 0, 0);
        }
      }

    __syncthreads();   // all reads of buf[cur] done; next tile's DMA drained (vmcnt(0))
  }

  // l: per-lane covers its h-half of m for q-row n=l32; merge halves
  {
    float v = lsum;
    v += __shfl_xor(v, 32);
    if (lane < 32)
      lpart[(size_t)kh * ROWS + (size_t)b * NSEQ + q0 + wv * 32 + l32] = v;
  }
  float* ob = opart + (size_t)kh * ROWS * DIM + ((size_t)b * NSEQ + q0 + wv * 32) * DIM;
  for (int dt = 0; dt < 4; ++dt)
    for (int i = 0; i < 16; ++i) {
      int n = (i & 3) + 8 * (i >> 2) + 4 * h;   // 32x32 C/D row map (measured m74/m101)
      ob[n * DIM + dt * 32 + l32] = Oacc[dt][i];
    }
}

// ---------- combine fp32 partials, normalize, out = o @ Wp + bp (fp32 out) ----------
// 64 rows per block (512 blocks -> 2 blocks/CU; was 128 rows @ 1 block/CU).
__global__ __launch_bounds__(256, 2) void combine_proj_kernel(
    const float* __restrict__ opart, const float* __restrict__ lpart,
    const unsigned short* __restrict__ wpT, const float* __restrict__ bp,
    float* __restrict__ out) {
  __shared__ __align__(16) unsigned short WT[128 * 136];
  const int tid = threadIdx.x;
  const int wv = tid >> 6, lane = tid & 63, l16 = lane & 15, quad = lane >> 4;
  const int row0 = blockIdx.x * 64;

  for (int p = 0; p < 8; ++p) {
    int c = p * 256 + tid;
    int col = c >> 4, c16 = c & 15;
    *reinterpret_cast<US8*>(&WT[col * 136 + c16 * 8]) =
        *reinterpret_cast<const US8*>(wpT + col * 128 + c16 * 8);
  }
  __syncthreads();

  f32x4 acc[8];
  for (int g = 0; g < 8; ++g) acc[g] = f32x4{0.f, 0.f, 0.f, 0.f};
  const int arow = row0 + wv * 16 + l16;
  float linv = 1.f / (lpart[arow] + lpart[ROWS + arow]);
  for (int s = 0; s < 4; ++s) {
    const size_t base = (size_t)arow * DIM + s * 32 + quad * 8;
    float4 s0 = *reinterpret_cast<const float4*>(opart + base);
    float4 s1 = *reinterpret_cast<const float4*>(opart + base + 4);
    float4 u0 = *reinterpret_cast<const float4*>(opart + (size_t)ROWS * DIM + base);
    float4 u1 = *reinterpret_cast<const float4*>(opart + (size_t)ROWS * DIM + base + 4);
    US8 af;
    af.us[0]=f2bf((s0.x+u0.x)*linv); af.us[1]=f2bf((s0.y+u0.y)*linv);
    af.us[2]=f2bf((s0.z+u0.z)*linv); af.us[3]=f2bf((s0.w+u0.w)*linv);
    af.us[4]=f2bf((s1.x+u1.x)*linv); af.us[5]=f2bf((s1.y+u1.y)*linv);
    af.us[6]=f2bf((s1.z+u1.z)*linv); af.us[7]=f2bf((s1.w+u1.w)*linv);
    bf16x8 a = __builtin_bit_cast(bf16x8, af);
    for (int g = 0; g < 8; ++g) {
      bf16x8 bfr = *reinterpret_cast<const bf16x8*>(&WT[(g * 16 + l16) * 136 + s * 32 + quad * 8]);
      acc[g] = __builtin_amdgcn_mfma_f32_16x16x32_bf16(a, bfr, acc[g], 0, 0, 0);
    }
  }
  for (int g = 0; g < 8; ++g) {
    float bias = bp[g * 16 + l16];
    for (int r = 0; r < 4; ++r) {
      int orow = row0 + wv * 16 + quad * 4 + r;
      out[(size_t)orow * DIM + g * 16 + l16] = acc[g][r] + bias;
    }
  }
}

extern "C" void kernel_launch(void* const* d_in, const int* in_sizes, int n_in,
                              void* d_out, int out_size, void* d_ws, size_t ws_size,
                              hipStream_t stream) {
  (void)in_sizes; (void)n_in; (void)out_size; (void)ws_size;
  const float* x   = (const float*)d_in[0];
  const float* qg  = (const float*)d_in[1];
  const float* Wkv = (const float*)d_in[2];
  const float* bkv = (const float*)d_in[3];
  const float* Wp  = (const float*)d_in[4];
  const float* bp  = (const float*)d_in[5];
  float* out = (float*)d_out;

  // workspace: 3x bf16 bufs 25.2MB | weights 96KB | l 256KB | O partials (fp32, KH=2) 33.6MB
  unsigned short* qbf  = (unsigned short*)d_ws;
  unsigned short* kbf  = qbf + (size_t)ROWS * DIM;
  unsigned short* vtbf = kbf + (size_t)ROWS * DIM;
  unsigned short* wkvT = vtbf + (size_t)ROWS * DIM;
  unsigned short* wpT  = wkvT + 256 * 128;
  float* lpart = (float*)(wpT + 128 * 128);
  float* opart = lpart + (size_t)KH * ROWS;

  hipLaunchKernelGGL(prep_kernel, dim3(96), dim3(256), 0, stream, Wkv, Wp, wkvT, wpT);
  hipLaunchKernelGGL(kv_kernel, dim3(512 + 2048), dim3(256), 0, stream,
                     x, wkvT, bkv, qg, kbf, vtbf, qbf);
  hipLaunchKernelGGL(attn_kernel, dim3(8 * 32 * KH), dim3(256), 0, stream, kbf, qbf, vtbf, opart, lpart);
  hipLaunchKernelGGL(combine_proj_kernel, dim3(ROWS / 64), dim3(256), 0, stream, opart, lpart, wpT, bp, out);
}

// Round 2
// 172.588 us; speedup vs baseline: 1.0975x; 1.0745x over previous
//
#include <hip/hip_runtime.h>

// ---------- types / helpers ----------
typedef __bf16 bf16x8 __attribute__((ext_vector_type(8)));
typedef float f32x4 __attribute__((ext_vector_type(4)));
typedef float f32x16 __attribute__((ext_vector_type(16)));

struct alignas(16) US8 { unsigned short us[8]; };

static __device__ inline unsigned short f2bf(float f) {
  union { float f; unsigned u; } v; v.f = f;
  unsigned r = v.u + 0x7fffu + ((v.u >> 16) & 1u);   // RNE
  return (unsigned short)(r >> 16);
}

static __device__ inline void gload16(const unsigned short* g, unsigned short* l) {
  // direct-to-LDS DMA, 16B/lane; LDS dest = wave-uniform base + lane*16
  __builtin_amdgcn_global_load_lds(
      (const __attribute__((address_space(1))) void*)g,
      (__attribute__((address_space(3))) void*)l, 16, 0, 0);
}

// B=8, N=4096, D=128.  32768 total rows.
#define NSEQ 4096
#define DIM 128
#define ROWS 32768
#define KH 2                      // cross-block key splits in attn

// log2(e)/sqrt(128): folded into q so S exits QK^T already in log2 domain
#define EXPC (1.4426950408889634f * 0.08838834764831845f)

// ---------- prep: weight transposes to bf16, wide (96 blocks) ----------
__global__ void prep_kernel(const float* __restrict__ Wkv, const float* __restrict__ Wp,
                            unsigned short* __restrict__ wkvT, unsigned short* __restrict__ wpT) {
  const int t = threadIdx.x;
  const int d = (t & 63) * 2;
  if (blockIdx.x < 64) {
    const int col = blockIdx.x * 4 + (t >> 6);
    unsigned short lo = f2bf(Wkv[d * 256 + col]);
    unsigned short hi = f2bf(Wkv[(d + 1) * 256 + col]);
    *reinterpret_cast<unsigned*>(&wkvT[col * 128 + d]) = (unsigned)lo | ((unsigned)hi << 16);
  } else {
    const int col = (blockIdx.x - 64) * 4 + (t >> 6);
    unsigned short lo = f2bf(Wp[d * 128 + col]);
    unsigned short hi = f2bf(Wp[(d + 1) * 128 + col]);
    *reinterpret_cast<unsigned*>(&wpT[col * 128 + d]) = (unsigned)lo | ((unsigned)hi << 16);
  }
}

// ---------- kv = x @ Wkv + bkv -> k_bf (row-major), v BLOCKED+PERMUTED; q blocked cast ----------
// 64 rows per block (512 GEMM blocks -> 2 blocks/CU).
// Blocked V layout per batch: [tile(64 keys)][chunk 16][lane 64][8] where chunk=(mg,dh):
//   element (chunk, l, j) = V[m' = mg*8+j][d = dh*64+l], m' = key order with bit2<->bit3
//   swapped per 16-block (matches 32x32 MFMA C/D->A reg order in attn's PV).
// Blocked q_hat layout per batch: [tile(64 rows)][kc 16][lane 64][8]:
//   element = q_hat[row = tile*64+l][d = kc*8+j].
__global__ __launch_bounds__(256, 2) void kv_kernel(
    const float* __restrict__ x, const unsigned short* __restrict__ wkvT,
    const float* __restrict__ bkv, const float* __restrict__ q,
    unsigned short* __restrict__ kout, unsigned short* __restrict__ vtout,
    unsigned short* __restrict__ qo) {
  const int tid = threadIdx.x;
  if (blockIdx.x >= 512) {                  // q scale+cast tail blocks -> blocked layout
    int i = ((blockIdx.x - 512) * 256 + tid) * 8;
    const float4* p = reinterpret_cast<const float4*>(q + i);
    float4 a = p[0], b = p[1];
    US8 o;
    o.us[0]=f2bf(a.x*EXPC); o.us[1]=f2bf(a.y*EXPC); o.us[2]=f2bf(a.z*EXPC); o.us[3]=f2bf(a.w*EXPC);
    o.us[4]=f2bf(b.x*EXPC); o.us[5]=f2bf(b.y*EXPC); o.us[6]=f2bf(b.z*EXPC); o.us[7]=f2bf(b.w*EXPC);
    int row = i >> 7, d0 = i & 127;
    int bb = row >> 12, n = row & (NSEQ - 1), tile = n >> 6, l = n & 63, kc = d0 >> 3;
    *reinterpret_cast<US8*>(qo + (size_t)bb * NSEQ * DIM + tile * 8192 + kc * 512 + l * 8) = o;
    return;
  }
  __shared__ __align__(16) unsigned short WT[256 * 136];   // [col][d] stride 136 (69.6 KB)
  const int wv = tid >> 6, lane = tid & 63, l16 = lane & 15, quad = lane >> 4;
  const int row0 = blockIdx.x * 64;

  for (int p = 0; p < 16; ++p) {            // 4096 US8 chunks, b128 both sides
    int c = p * 256 + tid;
    int col = c >> 4, c16 = c & 15;
    *reinterpret_cast<US8*>(&WT[col * 136 + c16 * 8]) =
        *reinterpret_cast<const US8*>(wkvT + col * 128 + c16 * 8);
  }
  __syncthreads();

  bf16x8 afrag[4];
  const int arow = row0 + wv * 16 + l16;
  for (int s = 0; s < 4; ++s) {
    const float4* xp = reinterpret_cast<const float4*>(x + (size_t)arow * DIM + s * 32 + quad * 8);
    float4 u0 = xp[0], u1 = xp[1];
    US8 af;
    af.us[0]=f2bf(u0.x); af.us[1]=f2bf(u0.y); af.us[2]=f2bf(u0.z); af.us[3]=f2bf(u0.w);
    af.us[4]=f2bf(u1.x); af.us[5]=f2bf(u1.y); af.us[6]=f2bf(u1.z); af.us[7]=f2bf(u1.w);
    afrag[s] = __builtin_bit_cast(bf16x8, af);
  }
  f32x4 acc[16];
  for (int g = 0; g < 16; ++g) acc[g] = f32x4{0.f, 0.f, 0.f, 0.f};
  for (int s = 0; s < 4; ++s)
    for (int g = 0; g < 16; ++g) {
      bf16x8 bfr = *reinterpret_cast<const bf16x8*>(&WT[(g * 16 + l16) * 136 + s * 32 + quad * 8]);
      acc[g] = __builtin_amdgcn_mfma_f32_16x16x32_bf16(afrag[s], bfr, acc[g], 0, 0, 0);
    }

  // k half: direct stores (row-major)
  for (int g = 0; g < 8; ++g) {
    float bias = bkv[g * 16 + l16];
    for (int r = 0; r < 4; ++r) {
      int orow = row0 + wv * 16 + quad * 4 + r;   // C/D: row=quad*4+r, col=l16
      kout[(size_t)orow * DIM + g * 16 + l16] = f2bf(acc[g][r] + bias);
    }
  }
  // v half: transpose through LDS (stride 72), then blocked+permuted b128 global stores
  __syncthreads();
  unsigned short* LDSt = WT;                // [d][n_local 64] stride 72
  for (int g = 0; g < 8; ++g) {
    float bias = bkv[128 + g * 16 + l16];
    for (int r = 0; r < 4; ++r)
      LDSt[(g * 16 + l16) * 72 + wv * 16 + quad * 4 + r] = f2bf(acc[g + 8][r] + bias);
  }
  __syncthreads();
  const int bb = row0 >> 12;
  const int tile = (row0 & (NSEQ - 1)) >> 6;
  unsigned short* vbo = vtout + (size_t)bb * NSEQ * DIM + (size_t)tile * 8192;
  for (int p = 0; p < 4; ++p) {             // 1024 16B units: 16 chunks x 64 lanes
    int c = p * 256 + tid;
    int idx = c >> 6, l = c & 63;
    int mg = idx >> 1, dh = idx & 1, d = dh * 64 + l;
    int nb = (mg >> 1) * 16 + (mg & 1) * 4;   // first 4-run (bit2<->3 swap)
    uint2 lo = *reinterpret_cast<const uint2*>(&LDSt[d * 72 + nb]);
    uint2 hi = *reinterpret_cast<const uint2*>(&LDSt[d * 72 + nb + 8]);
    uint4 o{lo.x, lo.y, hi.x, hi.y};
    *reinterpret_cast<uint4*>(vbo + (size_t)idx * 512 + l * 8) = o;
  }
}

// ---------- flash attention partials (32x32x16 MFMA, register-P, double-buffered DMA) ----------
// grid 512 = 8 batches (blockIdx&7) x 32 q-tiles (128 rows) x 2 key-splits.
// Block 256 thr = 4 q-waves x 32 rows; TWO 64-key K-hat/V tiles in LDS (64 KB -> 2 blocks/CU).
// Loop = { issue DMA for tile t+1 into other buffer; compute tile t; one __syncthreads }.
// Softmax path minimized: raw v_exp_f32 (log2-domain scores), v_perm truncate-pack (1 op),
// l-rowsum moved OFF the VALU onto the matrix pipe via an all-ones-B MFMA per P-fragment.
__global__ __launch_bounds__(256, 2) void attn_kernel(
    const unsigned short* __restrict__ kbuf, const unsigned short* __restrict__ qblk,
    const unsigned short* __restrict__ vblk,
    float* __restrict__ opart, float* __restrict__ lpart) {
  __shared__ __align__(16) unsigned short SH[32768];   // 2 x (Ksh 8192 | Vsh 8192) = 64 KB
  const int tid = threadIdx.x;
  const int wv = tid >> 6, lane = tid & 63, l32 = lane & 31, h = lane >> 5;
  const int b = blockIdx.x & 7;
  const int t = blockIdx.x >> 3;
  const int q0 = (t & 31) * 128;
  const int kh = t >> 5;
  const int key0 = kh * (NSEQ / KH);
  const unsigned short* kb = kbuf + (size_t)b * NSEQ * DIM;
  const unsigned short* qb = qblk + (size_t)b * NSEQ * DIM;
  const unsigned short* vb = vblk + (size_t)b * NSEQ * DIM;

  // per-lane staging sources: 8 chunks/wave/tile, advance 8192 us per tile.
  // lofs = idx*512 covers K at [0,8192) and V at [8192,16384) within a buffer.
  const unsigned short* gsrc[8];
  int lofs[8];
#pragma unroll
  for (int c = 0; c < 8; ++c) {
    const int idx = wv * 8 + c;
    const unsigned short* p = (idx < 16) ? (qb + idx * 512) : (vb + (size_t)(idx - 16) * 512);
    gsrc[c] = p + (size_t)(key0 >> 6) * 8192 + lane * 8;
    lofs[c] = idx * 512;
  }

  constexpr int NT = NSEQ / KH / 64;
  // prologue: stage tile 0 into buffer 0 (overlaps with kfrag loads below)
#pragma unroll
  for (int c = 0; c < 8; ++c) gload16(gsrc[c], &SH[lofs[c]]);

  // B-operand frags: this wave's 32 q-rows of k. B[k=h*8+j][n=l32]
  bf16x8 kfrag[8];
  for (int ks = 0; ks < 8; ++ks)
    kfrag[ks] = __builtin_bit_cast(bf16x8, *reinterpret_cast<const US8*>(
        kb + (size_t)(q0 + wv * 32 + l32) * DIM + ks * 16 + h * 8));

  // all-ones B operand for the l-rowsum MFMA (bf16 1.0 = 0x3F80)
  US8 one8;
#pragma unroll
  for (int j = 0; j < 8; ++j) one8.us[j] = 0x3F80;
  const bf16x8 vones = __builtin_bit_cast(bf16x8, one8);

  f32x16 Oacc[4];
  for (int dt = 0; dt < 4; ++dt)
    for (int i = 0; i < 16; ++i) Oacc[dt][i] = 0.f;
  f32x16 Lacc;
  for (int i = 0; i < 16; ++i) Lacc[i] = 0.f;

  __syncthreads();                          // tile 0 staged (vmcnt(0) + barrier)

  for (int it = 0; it < NT; ++it) {
    const int cur = (it & 1) << 14;         // 0 / 16384
    if (it + 1 < NT) {                      // issue next tile's DMA into other buffer
      const int nxt = cur ^ 16384;
#pragma unroll
      for (int c = 0; c < 8; ++c)
        gload16(gsrc[c] + (size_t)(it + 1) * 8192, &SH[nxt + lofs[c]]);
    }
    const unsigned short* Ksh = SH + cur;
    const unsigned short* Vsh = Ksh + 8192;

    // S^T tiles: D[m 32][n 32] = sum_ks A(K-hat)[m][k] * B(k-rows)[k][n]
    f32x16 S0, S1;
    for (int i = 0; i < 16; ++i) { S0[i] = 0.f; S1[i] = 0.f; }
    __builtin_amdgcn_s_setprio(1);
#pragma unroll
    for (int ks = 0; ks < 8; ++ks) {
      const unsigned short* kc = &Ksh[(ks * 2 + h) * 512];
      bf16x8 a0 = *reinterpret_cast<const bf16x8*>(&kc[l32 * 8]);
      bf16x8 a1 = *reinterpret_cast<const bf16x8*>(&kc[(32 + l32) * 8]);
      S0 = __builtin_amdgcn_mfma_f32_32x32x16_bf16(a0, kfrag[ks], S0, 0, 0, 0);
      S1 = __builtin_amdgcn_mfma_f32_32x32x16_bf16(a1, kfrag[ks], S1, 0, 0, 0);
    }
    __builtin_amdgcn_s_setprio(0);

    // P = exp2(S^T) truncated to bf16, packed in-lane: frag (T,s) = regs s*8..s*8+7.
    // v_exp_f32 direct (scores pre-scaled by log2e), v_perm_b32 packs two truncated
    // bf16 from the high halves of (e0,e1) in ONE op.
    bf16x8 pf[2][2];
#pragma unroll
    for (int T = 0; T < 2; ++T) {
      unsigned pk[8];
#pragma unroll
      for (int i2 = 0; i2 < 8; ++i2) {
        float e0 = __builtin_amdgcn_exp2f(T ? S1[i2 * 2] : S0[i2 * 2]);
        float e1 = __builtin_amdgcn_exp2f(T ? S1[i2 * 2 + 1] : S0[i2 * 2 + 1]);
        pk[i2] = __builtin_amdgcn_perm(__builtin_bit_cast(unsigned, e1),
                                       __builtin_bit_cast(unsigned, e0), 0x07060302u);
      }
      pf[T][0] = __builtin_bit_cast(bf16x8, uint4{pk[0], pk[1], pk[2], pk[3]});
      pf[T][1] = __builtin_bit_cast(bf16x8, uint4{pk[4], pk[5], pk[6], pk[7]});
    }

    // O[n][d] += P[n][m] * V[m][d]: A = pf (regs), B = Vsh chunks (mg = 4T+2s+h).
    // Lacc row-sums the SAME truncated-bf16 P via ones-B MFMA (exact consistency with PV).
    __builtin_amdgcn_s_setprio(1);
#pragma unroll
    for (int T = 0; T < 2; ++T)
#pragma unroll
      for (int s = 0; s < 2; ++s) {
        const int mg = 4 * T + 2 * s + h;
#pragma unroll
        for (int dt = 0; dt < 4; ++dt) {
          bf16x8 bv = *reinterpret_cast<const bf16x8*>(
              &Vsh[(mg * 2 + (dt >> 1)) * 512 + ((dt & 1) * 32 + l32) * 8]);
          Oacc[dt] = __builtin_amdgcn_mfma_f32_32x32x16_bf16(pf[T][s], bv, Oacc[dt], 0, 0, 0);
        }
        Lacc = __builtin_amdgcn_mfma_f32_32x32x16_bf16(pf[T][s], vones, Lacc, 0, 0, 0);
      }
    __builtin_amdgcn_s_setprio(0);

    __syncthreads();   // all reads of buf[cur] done; next tile's DMA drained (vmcnt(0))
  }

  // l from Lacc: D[n][col] = rowsum(P) for every col; lane with l32==n (h matching
  // n's bit2) writes. 16 compile-time-indexed predicated stores, once per kernel.
#pragma unroll
  for (int i = 0; i < 16; ++i) {
    int n = (i & 3) + 8 * (i >> 2) + 4 * h;   // 32x32 C/D row map (measured m74/m101)
    if (l32 == n)
      lpart[(size_t)kh * ROWS + (size_t)b * NSEQ + q0 + wv * 32 + n] = Lacc[i];
  }
  float* ob = opart + (size_t)kh * ROWS * DIM + ((size_t)b * NSEQ + q0 + wv * 32) * DIM;
  for (int dt = 0; dt < 4; ++dt)
    for (int i = 0; i < 16; ++i) {
      int n = (i & 3) + 8 * (i >> 2) + 4 * h;
      ob[n * DIM + dt * 32 + l32] = Oacc[dt][i];
    }
}

// ---------- combine fp32 partials, normalize, out = o @ Wp + bp (fp32 out) ----------
// 64 rows per block (512 blocks -> 2 blocks/CU).
__global__ __launch_bounds__(256, 2) void combine_proj_kernel(
    const float* __restrict__ opart, const float* __restrict__ lpart,
    const unsigned short* __restrict__ wpT, const float* __restrict__ bp,
    float* __restrict__ out) {
  __shared__ __align__(16) unsigned short WT[128 * 136];
  const int tid = threadIdx.x;
  const int wv = tid >> 6, lane = tid & 63, l16 = lane & 15, quad = lane >> 4;
  const int row0 = blockIdx.x * 64;

  for (int p = 0; p < 8; ++p) {
    int c = p * 256 + tid;
    int col = c >> 4, c16 = c & 15;
    *reinterpret_cast<US8*>(&WT[col * 136 + c16 * 8]) =
        *reinterpret_cast<const US8*>(wpT + col * 128 + c16 * 8);
  }
  __syncthreads();

  f32x4 acc[8];
  for (int g = 0; g < 8; ++g) acc[g] = f32x4{0.f, 0.f, 0.f, 0.f};
  const int arow = row0 + wv * 16 + l16;
  float linv = 1.f / (lpart[arow] + lpart[ROWS + arow]);
  for (int s = 0; s < 4; ++s) {
    const size_t base = (size_t)arow * DIM + s * 32 + quad * 8;
    float4 s0 = *reinterpret_cast<const float4*>(opart + base);
    float4 s1 = *reinterpret_cast<const float4*>(opart + base + 4);
    float4 u0 = *reinterpret_cast<const float4*>(opart + (size_t)ROWS * DIM + base);
    float4 u1 = *reinterpret_cast<const float4*>(opart + (size_t)ROWS * DIM + base + 4);
    US8 af;
    af.us[0]=f2bf((s0.x+u0.x)*linv); af.us[1]=f2bf((s0.y+u0.y)*linv);
    af.us[2]=f2bf((s0.z+u0.z)*linv); af.us[3]=f2bf((s0.w+u0.w)*linv);
    af.us[4]=f2bf((s1.x+u1.x)*linv); af.us[5]=f2bf((s1.y+u1.y)*linv);
    af.us[6]=f2bf((s1.z+u1.z)*linv); af.us[7]=f2bf((s1.w+u1.w)*linv);
    bf16x8 a = __builtin_bit_cast(bf16x8, af);
    for (int g = 0; g < 8; ++g) {
      bf16x8 bfr = *reinterpret_cast<const bf16x8*>(&WT[(g * 16 + l16) * 136 + s * 32 + quad * 8]);
      acc[g] = __builtin_amdgcn_mfma_f32_16x16x32_bf16(a, bfr, acc[g], 0, 0, 0);
    }
  }
  for (int g = 0; g < 8; ++g) {
    float bias = bp[g * 16 + l16];
    for (int r = 0; r < 4; ++r) {
      int orow = row0 + wv * 16 + quad * 4 + r;
      out[(size_t)orow * DIM + g * 16 + l16] = acc[g][r] + bias;
    }
  }
}

extern "C" void kernel_launch(void* const* d_in, const int* in_sizes, int n_in,
                              void* d_out, int out_size, void* d_ws, size_t ws_size,
                              hipStream_t stream) {
  (void)in_sizes; (void)n_in; (void)out_size; (void)ws_size;
  const float* x   = (const float*)d_in[0];
  const float* qg  = (const float*)d_in[1];
  const float* Wkv = (const float*)d_in[2];
  const float* bkv = (const float*)d_in[3];
  const float* Wp  = (const float*)d_in[4];
  const float* bp  = (const float*)d_in[5];
  float* out = (float*)d_out;

  // workspace: 3x bf16 bufs 25.2MB | weights 96KB | l 256KB | O partials (fp32, KH=2) 33.6MB
  unsigned short* qbf  = (unsigned short*)d_ws;
  unsigned short* kbf  = qbf + (size_t)ROWS * DIM;
  unsigned short* vtbf = kbf + (size_t)ROWS * DIM;
  unsigned short* wkvT = vtbf + (size_t)ROWS * DIM;
  unsigned short* wpT  = wkvT + 256 * 128;
  float* lpart = (float*)(wpT + 128 * 128);
  float* opart = lpart + (size_t)KH * ROWS;

  hipLaunchKernelGGL(prep_kernel, dim3(96), dim3(256), 0, stream, Wkv, Wp, wkvT, wpT);
  hipLaunchKernelGGL(kv_kernel, dim3(512 + 2048), dim3(256), 0, stream,
                     x, wkvT, bkv, qg, kbf, vtbf, qbf);
  hipLaunchKernelGGL(attn_kernel, dim3(8 * 32 * KH), dim3(256), 0, stream, kbf, qbf, vtbf, opart, lpart);
  hipLaunchKernelGGL(combine_proj_kernel, dim3(ROWS / 64), dim3(256), 0, stream, opart, lpart, wpT, bp, out);
}